// Round 6
// baseline (159.311 us; speedup 1.0000x reference)
//
#include <hip/hip_runtime.h>
#include <hip/hip_fp16.h>

#define NB      576          // 9 waves; 1152 = 576*2 -> 2 rows/thread
#define ROWS    2
#define NBATCH  2            // batches per block (one W-panel read serves both)
#define N_ROUTE 1152
#define C_IN    8
#define C_OUT   16
#define RS      9            // P row stride in u32 (8 data + 1 pad); gcd(9,32)=1
#define NWAVE   9
#define NPASS   8            // 1152 rows / 144 rows-per-pass

// 6-step DPP wave-64 sum; full sum lands in lane 63.
template<int CTRL>
__device__ __forceinline__ float dpp_add(float v) {
    int t = __builtin_amdgcn_update_dpp(0, __float_as_int(v), CTRL, 0xF, 0xF, true);
    return v + __int_as_float(t);
}
__device__ __forceinline__ float wave_sum63(float v) {
    v = dpp_add<0x111>(v);   // row_shr:1
    v = dpp_add<0x112>(v);   // row_shr:2
    v = dpp_add<0x114>(v);   // row_shr:4
    v = dpp_add<0x118>(v);   // row_shr:8
    v = dpp_add<0x142>(v);   // row_bcast:15
    v = dpp_add<0x143>(v);   // row_bcast:31
    return v;
}

__global__ __launch_bounds__(NB, 3)   // cap VGPR ~170: 9-wave block needs 3 waves on one SIMD
void capsule_routing(const float* __restrict__ x,
                     const float* __restrict__ W,
                     float* __restrict__ out)
{
    __shared__ unsigned int P[NBATCH][N_ROUTE * RS];  // fp16x2 priors, 82944 B
    __shared__ float red[NWAVE][20];                  // per-wave partials: 16 s + [16]=Z
    __shared__ float vfin[16];

    const int t    = threadIdx.x;
    const int lane = t & 63;
    const int wid  = t >> 6;

    // ---- c->XCD swizzle: same-capsule blocks share an XCD's L2 (W resident) ----
    // grid = 1280 = 10 capsules x 128 batch-pairs; assume XCD = blockIdx % 8.
    const int g   = blockIdx.x;
    const int xcd = g & 7;
    const int j   = g >> 3;              // 0..159 within XCD
    int c, pb;
    if (j < 128) { c = xcd;              pb = j; }
    else         { const int jj = j - 128;
                   c = 8 + (xcd >> 2);   pb = ((xcd & 3) << 5) + jj; }
    const int b0 = pb << 1;              // batches b0, b0+1

    // ---------------- Phase A: one W read serves both batches ----------------
    {
        const int og = t & 3;            // o-quad
        const int nl = t >> 2;           // 0..143
        const float* __restrict__ xb0 = x + (size_t)b0 * (N_ROUTE * C_IN);
        const float* __restrict__ xb1 = xb0 + (N_ROUTE * C_IN);
        const float* __restrict__ Wc  = W + (size_t)c * (N_ROUTE * C_IN * C_OUT);
        #pragma unroll 2
        for (int pp = 0; pp < NPASS; ++pp) {
            const int n = pp * 144 + nl;
            const float4 xa0 = *reinterpret_cast<const float4*>(xb0 + n * C_IN);
            const float4 xa1 = *reinterpret_cast<const float4*>(xb0 + n * C_IN + 4);
            const float4 xc0 = *reinterpret_cast<const float4*>(xb1 + n * C_IN);
            const float4 xc1 = *reinterpret_cast<const float4*>(xb1 + n * C_IN + 4);
            const float xs0[8] = {xa0.x, xa0.y, xa0.z, xa0.w, xa1.x, xa1.y, xa1.z, xa1.w};
            const float xs1[8] = {xc0.x, xc0.y, xc0.z, xc0.w, xc1.x, xc1.y, xc1.z, xc1.w};
            const float* __restrict__ wp = Wc + (size_t)n * (C_IN * C_OUT) + (og << 2);
            float4 a0 = make_float4(0.f, 0.f, 0.f, 0.f);
            float4 a1 = make_float4(0.f, 0.f, 0.f, 0.f);
            #pragma unroll
            for (int i = 0; i < 8; ++i) {
                const float4 w = *reinterpret_cast<const float4*>(wp + i * C_OUT);
                a0.x = fmaf(xs0[i], w.x, a0.x);  a1.x = fmaf(xs1[i], w.x, a1.x);
                a0.y = fmaf(xs0[i], w.y, a0.y);  a1.y = fmaf(xs1[i], w.y, a1.y);
                a0.z = fmaf(xs0[i], w.z, a0.z);  a1.z = fmaf(xs1[i], w.z, a1.z);
                a0.w = fmaf(xs0[i], w.w, a0.w);  a1.w = fmaf(xs1[i], w.w, a1.w);
            }
            const int base = n * RS + (og << 1);
            __half2 h;
            h = __floats2half2_rn(a0.x, a0.y); P[0][base + 0] = *reinterpret_cast<unsigned int*>(&h);
            h = __floats2half2_rn(a0.z, a0.w); P[0][base + 1] = *reinterpret_cast<unsigned int*>(&h);
            h = __floats2half2_rn(a1.x, a1.y); P[1][base + 0] = *reinterpret_cast<unsigned int*>(&h);
            h = __floats2half2_rn(a1.z, a1.w); P[1][base + 1] = *reinterpret_cast<unsigned int*>(&h);
        }
    }
    __syncthreads();

    // ---------------- Routing: per batch, fused single P-pass per iteration ----------------
    #pragma unroll
    for (int bt = 0; bt < NBATCH; ++bt) {
        float vprev[16];
        #pragma unroll
        for (int o = 0; o < 16; ++o) vprev[o] = 0.f;
        float lg[ROWS] = {0.f, 0.f};

        #pragma unroll
        for (int it = 0; it < 3; ++it) {
            float sp[16];
            #pragma unroll
            for (int o = 0; o < 16; ++o) sp[o] = 0.f;
            float zp = 0.f;

            #pragma unroll
            for (int k = 0; k < ROWS; ++k) {
                const unsigned int* __restrict__ pr = &P[bt][(t + k * NB) * RS];
                float pv[16];
                #pragma unroll
                for (int jj = 0; jj < 8; ++jj) {
                    __half2 h = *reinterpret_cast<const __half2*>(&pr[jj]);
                    float2 f = __half22float2(h);
                    pv[2 * jj]     = f.x;
                    pv[2 * jj + 1] = f.y;
                }
                float d = 0.f;
                #pragma unroll
                for (int o = 0; o < 16; ++o) d = fmaf(pv[o], vprev[o], d);
                lg[k] += d;                      // it0: vprev=0 -> lg stays 0
                const float e = __expf(lg[k]);   // |lg| small; fp32 exp safe, no max-sub
                zp += e;
                #pragma unroll
                for (int o = 0; o < 16; ++o) sp[o] = fmaf(e, pv[o], sp[o]);
            }

            // 17-value wave reduction on the VALU pipe (DPP)
            #pragma unroll
            for (int o = 0; o < 16; ++o) sp[o] = wave_sum63(sp[o]);
            zp = wave_sum63(zp);
            if (lane == 63) {
                #pragma unroll
                for (int o = 0; o < 16; ++o) red[wid][o] = sp[o];
                red[wid][16] = zp;
            }
            __syncthreads();                     // red writes -> combine

            if (t < 16) {
                float tot = 0.f, Zt = 0.f;
                #pragma unroll
                for (int w2 = 0; w2 < NWAVE; ++w2) {
                    tot += red[w2][t];
                    Zt  += red[w2][16];
                }
                const float so = tot / Zt;
                float sq = so * so;
                #pragma unroll
                for (int off = 8; off >= 1; off >>= 1) sq += __shfl_xor(sq, off);
                const float fac = sqrtf(sq) / (1.f + sq);
                const float vo  = so * fac;
                if (it == 2) out[((size_t)(((c << 8) + b0 + bt)) << 4) + t] = vo;
                else         vfin[t] = vo;
            }
            if (!(bt == NBATCH - 1 && it == 2))
                __syncthreads();                 // vfin ready / protect red reuse
            if (it < 2) {
                const float4 v0 = *reinterpret_cast<const float4*>(&vfin[0]);
                const float4 v1 = *reinterpret_cast<const float4*>(&vfin[4]);
                const float4 v2 = *reinterpret_cast<const float4*>(&vfin[8]);
                const float4 v3 = *reinterpret_cast<const float4*>(&vfin[12]);
                vprev[0]=v0.x;  vprev[1]=v0.y;  vprev[2]=v0.z;  vprev[3]=v0.w;
                vprev[4]=v1.x;  vprev[5]=v1.y;  vprev[6]=v1.z;  vprev[7]=v1.w;
                vprev[8]=v2.x;  vprev[9]=v2.y;  vprev[10]=v2.z; vprev[11]=v2.w;
                vprev[12]=v3.x; vprev[13]=v3.y; vprev[14]=v3.z; vprev[15]=v3.w;
            }
        }
    }
}

extern "C" void kernel_launch(void* const* d_in, const int* in_sizes, int n_in,
                              void* d_out, int out_size, void* d_ws, size_t ws_size,
                              hipStream_t stream)
{
    const float* x   = (const float*)d_in[0];
    const float* W   = (const float*)d_in[1];
    float*       out = (float*)d_out;
    capsule_routing<<<dim3(10 * 128), dim3(NB), 0, stream>>>(x, W, out);
}

// Round 7
// 137.571 us; speedup vs baseline: 1.1580x; 1.1580x over previous
//
#include <hip/hip_runtime.h>
#include <hip/hip_fp16.h>

#define NB    384            // 6 waves; 1152 = 384*3 -> exactly 3 rows/thread
#define ROWS  3
#define N_ROUTE 1152
#define C_IN  8
#define C_OUT 16

// 6-step DPP wave-64 sum; full sum lands in lane 63 (others hold partials).
template<int CTRL>
__device__ __forceinline__ float dpp_add(float v) {
    int t = __builtin_amdgcn_update_dpp(0, __float_as_int(v), CTRL, 0xF, 0xF, true);
    return v + __int_as_float(t);
}
__device__ __forceinline__ float wave_sum63(float v) {
    v = dpp_add<0x111>(v);   // row_shr:1
    v = dpp_add<0x112>(v);   // row_shr:2
    v = dpp_add<0x114>(v);   // row_shr:4
    v = dpp_add<0x118>(v);   // row_shr:8  -> lanes 15/31/47/63 hold row sums
    v = dpp_add<0x142>(v);   // row_bcast:15
    v = dpp_add<0x143>(v);   // row_bcast:31 -> lane 63 = full sum
    return v;
}

// P: fp16x2-packed priors, rows of 8 u32 at stride 8 (no pad), XOR-swizzled:
// logical word j lives at physical j ^ ((n>>2)&7). Both write and read
// patterns land 16 lanes on 8 banks = 2-way conflict = free.
// 36.9KB P + scratch -> 4 blocks/CU = 24 waves (75% theoretical occupancy).
__global__ __launch_bounds__(NB, 2)
void capsule_routing(const float* __restrict__ x,
                     const float* __restrict__ W,
                     float* __restrict__ out)
{
    __shared__ unsigned int P[N_ROUTE * 8];   // 36864 B
    __shared__ float red[6][20];              // per-wave partials: 16 s + [16]=Z
    __shared__ float vfin[16];                // broadcast v

    const int t    = threadIdx.x;
    const int bid  = blockIdx.x;
    const int c    = bid >> 8;
    const int b    = bid & 255;
    const int lane = t & 63;
    const int wid  = t >> 6;

    // ---------------- Phase A: coalesced priors -> swizzled fp16 LDS ----------------
    {
        const int og = t & 3;                 // o-quad
        const int nl = t >> 2;                // 0..95
        const float* __restrict__ xb = x + (size_t)b * (N_ROUTE * C_IN);
        const float* __restrict__ Wc = W + (size_t)c * (N_ROUTE * C_IN * C_OUT);
        #pragma unroll 2
        for (int pp = 0; pp < 12; ++pp) {
            const int n = pp * 96 + nl;
            const float4 x0 = *reinterpret_cast<const float4*>(xb + n * C_IN);
            const float4 x1 = *reinterpret_cast<const float4*>(xb + n * C_IN + 4);
            const float xs[8] = {x0.x, x0.y, x0.z, x0.w, x1.x, x1.y, x1.z, x1.w};
            const float* __restrict__ wp = Wc + (size_t)n * (C_IN * C_OUT) + (og << 2);
            float4 acc = make_float4(0.f, 0.f, 0.f, 0.f);
            #pragma unroll
            for (int i = 0; i < 8; ++i) {
                const float4 w = *reinterpret_cast<const float4*>(wp + i * C_OUT);
                acc.x = fmaf(xs[i], w.x, acc.x);
                acc.y = fmaf(xs[i], w.y, acc.y);
                acc.z = fmaf(xs[i], w.z, acc.z);
                acc.w = fmaf(xs[i], w.w, acc.w);
            }
            const int s    = (n >> 2) & 7;
            const int base = n << 3;
            __half2 h0 = __floats2half2_rn(acc.x, acc.y);
            __half2 h1 = __floats2half2_rn(acc.z, acc.w);
            P[base + (((og << 1)    ) ^ s)] = *reinterpret_cast<unsigned int*>(&h0);
            P[base + (((og << 1) + 1) ^ s)] = *reinterpret_cast<unsigned int*>(&h1);
        }
    }
    __syncthreads();

    // ---------------- Routing: fused single P-pass per iteration ----------------
    float vprev[16];
    #pragma unroll
    for (int o = 0; o < 16; ++o) vprev[o] = 0.f;
    float lg[ROWS] = {0.f, 0.f, 0.f};

    #pragma unroll
    for (int it = 0; it < 3; ++it) {
        float sp[16];
        #pragma unroll
        for (int o = 0; o < 16; ++o) sp[o] = 0.f;
        float zp = (it == 0) ? (float)ROWS : 0.f;

        #pragma unroll
        for (int k = 0; k < ROWS; ++k) {
            const int n = t + k * NB;
            const int s = (n >> 2) & 7;
            const unsigned int* __restrict__ pr = &P[n << 3];
            __half2 h[8];
            #pragma unroll
            for (int j = 0; j < 8; ++j) {
                const unsigned int w = pr[j ^ s];
                h[j] = *reinterpret_cast<const __half2*>(&w);
            }
            float e;
            if (it == 0) {
                e = 1.f;                       // softmax of zeros = uniform
            } else {
                // logit[n] += dot(P[n], v)  — fma_mix: (f32)h * f32 + f32 fuses
                float d = 0.f;
                #pragma unroll
                for (int j = 0; j < 8; ++j) {
                    d = fmaf(__low2float(h[j]),  vprev[2 * j],     d);
                    d = fmaf(__high2float(h[j]), vprev[2 * j + 1], d);
                }
                lg[k] += d;
                e = __expf(lg[k]);             // |lg| small; no max-sub needed
                zp += e;
            }
            #pragma unroll
            for (int j = 0; j < 8; ++j) {
                sp[2 * j]     = fmaf(e, __low2float(h[j]),  sp[2 * j]);
                sp[2 * j + 1] = fmaf(e, __high2float(h[j]), sp[2 * j + 1]);
            }
        }

        // 17-value wave reduction on the VALU pipe (DPP), result in lane 63
        #pragma unroll
        for (int o = 0; o < 16; ++o) sp[o] = wave_sum63(sp[o]);
        zp = wave_sum63(zp);
        if (lane == 63) {
            #pragma unroll
            for (int o = 0; o < 16; ++o) red[wid][o] = sp[o];
            red[wid][16] = zp;
        }
        __syncthreads();                       // barrier 1: red ready

        if (t < 16) {
            float tot = 0.f, Zt = 0.f;
            #pragma unroll
            for (int w2 = 0; w2 < 6; ++w2) {
                tot += red[w2][t];
                Zt  += red[w2][16];
            }
            const float so = tot / Zt;         // s[o]
            float sq = so * so;                // 16-lane butterfly for ||s||^2
            #pragma unroll
            for (int off = 8; off >= 1; off >>= 1) sq += __shfl_xor(sq, off);
            const float fac = sqrtf(sq) / (1.f + sq);
            const float vo  = so * fac;
            if (it == 2) out[((size_t)bid << 4) + t] = vo;
            else         vfin[t] = vo;
        }
        if (it < 2) {
            __syncthreads();                   // barrier 2: vfin ready, red safe
            const float4 v0 = *reinterpret_cast<const float4*>(&vfin[0]);
            const float4 v1 = *reinterpret_cast<const float4*>(&vfin[4]);
            const float4 v2 = *reinterpret_cast<const float4*>(&vfin[8]);
            const float4 v3 = *reinterpret_cast<const float4*>(&vfin[12]);
            vprev[0]=v0.x;  vprev[1]=v0.y;  vprev[2]=v0.z;  vprev[3]=v0.w;
            vprev[4]=v1.x;  vprev[5]=v1.y;  vprev[6]=v1.z;  vprev[7]=v1.w;
            vprev[8]=v2.x;  vprev[9]=v2.y;  vprev[10]=v2.z; vprev[11]=v2.w;
            vprev[12]=v3.x; vprev[13]=v3.y; vprev[14]=v3.z; vprev[15]=v3.w;
        }
    }
}

extern "C" void kernel_launch(void* const* d_in, const int* in_sizes, int n_in,
                              void* d_out, int out_size, void* d_ws, size_t ws_size,
                              hipStream_t stream)
{
    const float* x   = (const float*)d_in[0];
    const float* W   = (const float*)d_in[1];
    float*       out = (float*)d_out;
    capsule_routing<<<dim3(10 * 256), dim3(NB), 0, stream>>>(x, W, out);
}

// Round 8
// 137.518 us; speedup vs baseline: 1.1585x; 1.0004x over previous
//
#include <hip/hip_runtime.h>
#include <hip/hip_fp16.h>

#define NB    384            // 6 waves; 1152 = 384*3 -> exactly 3 rows/thread
#define ROWS  3
#define N_ROUTE 1152
#define C_IN  8
#define C_OUT 16

// 6-step DPP wave-64 sum; full sum lands in lane 63 (others hold partials).
template<int CTRL>
__device__ __forceinline__ float dpp_add(float v) {
    int t = __builtin_amdgcn_update_dpp(0, __float_as_int(v), CTRL, 0xF, 0xF, true);
    return v + __int_as_float(t);
}
__device__ __forceinline__ float wave_sum63(float v) {
    v = dpp_add<0x111>(v);   // row_shr:1
    v = dpp_add<0x112>(v);   // row_shr:2
    v = dpp_add<0x114>(v);   // row_shr:4
    v = dpp_add<0x118>(v);   // row_shr:8  -> lanes 15/31/47/63 hold row sums
    v = dpp_add<0x142>(v);   // row_bcast:15
    v = dpp_add<0x143>(v);   // row_bcast:31 -> lane 63 = full sum
    return v;
}

// ---- Pre-pass: W fp32 -> fp16 in thread-local-contiguous layout ----
// Wh[c][n][og*32 + i*4 + q] = W[c][n][i*16 + og*4 + q]
// Total 2.95 MB: fits per-XCD L2 entirely -> W never falls to L3 again.
__global__ __launch_bounds__(256, 4)
void convert_w(const float* __restrict__ W, __half* __restrict__ Wh)
{
    const int tid = blockIdx.x * 256 + threadIdx.x;   // 368640 total
    const int cn  = tid >> 5;                         // c*1152 + n
    const int r   = tid & 31;
    const int og  = r >> 3;
    const int i   = r & 7;
    const float4 v = *reinterpret_cast<const float4*>(
        W + (size_t)cn * 128 + i * 16 + og * 4);
    __half2 a = __floats2half2_rn(v.x, v.y);
    __half2 b = __floats2half2_rn(v.z, v.w);
    uint2 o;
    o.x = *reinterpret_cast<unsigned int*>(&a);
    o.y = *reinterpret_cast<unsigned int*>(&b);
    *reinterpret_cast<uint2*>(Wh + (size_t)cn * 128 + og * 32 + i * 4) = o;
}

// P: fp16x2-packed priors, rows of 8 u32 at stride 8, XOR-swizzled
// (word j at physical j ^ ((n>>2)&7)): write & read are 2-way conflict = free.
template<bool F16W>
__global__ __launch_bounds__(NB, 2)
void capsule_routing(const float* __restrict__ x,
                     const float* __restrict__ W,
                     const __half* __restrict__ Wh,
                     float* __restrict__ out)
{
    __shared__ unsigned int P[N_ROUTE * 8];   // 36864 B
    __shared__ float red[6][20];              // per-wave partials: 16 s + [16]=Z
    __shared__ float vfin[16];                // broadcast v

    const int t    = threadIdx.x;
    const int bid  = blockIdx.x;
    const int c    = bid >> 8;
    const int b    = bid & 255;
    const int lane = t & 63;
    const int wid  = t >> 6;

    // ---------------- Phase A: coalesced priors -> swizzled fp16 LDS ----------------
    {
        const int og = t & 3;                 // o-quad
        const int nl = t >> 2;                // 0..95
        const float* __restrict__ xb = x + (size_t)b * (N_ROUTE * C_IN);
        #pragma unroll 2
        for (int pp = 0; pp < 12; ++pp) {
            const int n = pp * 96 + nl;
            const float4 x0 = *reinterpret_cast<const float4*>(xb + n * C_IN);
            const float4 x1 = *reinterpret_cast<const float4*>(xb + n * C_IN + 4);
            const float xs[8] = {x0.x, x0.y, x0.z, x0.w, x1.x, x1.y, x1.z, x1.w};
            float4 acc = make_float4(0.f, 0.f, 0.f, 0.f);
            if (F16W) {
                const uint4* __restrict__ wp = reinterpret_cast<const uint4*>(
                    Wh + (size_t)c * (N_ROUTE * 128) + (size_t)n * 128 + og * 32);
                const uint4 w0 = wp[0], w1 = wp[1], w2 = wp[2], w3 = wp[3];
                const unsigned int ww[16] = {w0.x, w0.y, w0.z, w0.w,
                                             w1.x, w1.y, w1.z, w1.w,
                                             w2.x, w2.y, w2.z, w2.w,
                                             w3.x, w3.y, w3.z, w3.w};
                #pragma unroll
                for (int i = 0; i < 8; ++i) {
                    const __half2 ha = *reinterpret_cast<const __half2*>(&ww[2 * i]);
                    const __half2 hb = *reinterpret_cast<const __half2*>(&ww[2 * i + 1]);
                    acc.x = fmaf(xs[i], __low2float(ha),  acc.x);
                    acc.y = fmaf(xs[i], __high2float(ha), acc.y);
                    acc.z = fmaf(xs[i], __low2float(hb),  acc.z);
                    acc.w = fmaf(xs[i], __high2float(hb), acc.w);
                }
            } else {
                const float* __restrict__ wp =
                    W + (size_t)c * (N_ROUTE * 128) + (size_t)n * 128 + (og << 2);
                #pragma unroll
                for (int i = 0; i < 8; ++i) {
                    const float4 w = *reinterpret_cast<const float4*>(wp + i * C_OUT);
                    acc.x = fmaf(xs[i], w.x, acc.x);
                    acc.y = fmaf(xs[i], w.y, acc.y);
                    acc.z = fmaf(xs[i], w.z, acc.z);
                    acc.w = fmaf(xs[i], w.w, acc.w);
                }
            }
            const int s    = (n >> 2) & 7;
            const int base = n << 3;
            __half2 h0 = __floats2half2_rn(acc.x, acc.y);
            __half2 h1 = __floats2half2_rn(acc.z, acc.w);
            P[base + (((og << 1)    ) ^ s)] = *reinterpret_cast<unsigned int*>(&h0);
            P[base + (((og << 1) + 1) ^ s)] = *reinterpret_cast<unsigned int*>(&h1);
        }
    }
    __syncthreads();

    // ---------------- Routing: fused single P-pass per iteration ----------------
    float vprev[16];
    #pragma unroll
    for (int o = 0; o < 16; ++o) vprev[o] = 0.f;
    float lg[ROWS] = {0.f, 0.f, 0.f};

    #pragma unroll
    for (int it = 0; it < 3; ++it) {
        float sp[16];
        #pragma unroll
        for (int o = 0; o < 16; ++o) sp[o] = 0.f;
        float zp = (it == 0) ? (float)ROWS : 0.f;

        #pragma unroll
        for (int k = 0; k < ROWS; ++k) {
            const int n = t + k * NB;
            const int s = (n >> 2) & 7;
            const unsigned int* __restrict__ pr = &P[n << 3];
            __half2 h[8];
            #pragma unroll
            for (int j = 0; j < 8; ++j) {
                const unsigned int w = pr[j ^ s];
                h[j] = *reinterpret_cast<const __half2*>(&w);
            }
            float e;
            if (it == 0) {
                e = 1.f;                       // softmax of zeros = uniform
            } else {
                float d = 0.f;                 // logit[n] += dot(P[n], v)
                #pragma unroll
                for (int j = 0; j < 8; ++j) {
                    d = fmaf(__low2float(h[j]),  vprev[2 * j],     d);
                    d = fmaf(__high2float(h[j]), vprev[2 * j + 1], d);
                }
                lg[k] += d;
                e = __expf(lg[k]);             // |lg| small; no max-sub needed
                zp += e;
            }
            #pragma unroll
            for (int j = 0; j < 8; ++j) {
                sp[2 * j]     = fmaf(e, __low2float(h[j]),  sp[2 * j]);
                sp[2 * j + 1] = fmaf(e, __high2float(h[j]), sp[2 * j + 1]);
            }
        }

        // 17-value wave reduction on the VALU pipe (DPP), result in lane 63
        #pragma unroll
        for (int o = 0; o < 16; ++o) sp[o] = wave_sum63(sp[o]);
        zp = wave_sum63(zp);
        if (lane == 63) {
            #pragma unroll
            for (int o = 0; o < 16; ++o) red[wid][o] = sp[o];
            red[wid][16] = zp;
        }
        __syncthreads();                       // barrier 1: red ready

        if (t < 16) {
            float tot = 0.f, Zt = 0.f;
            #pragma unroll
            for (int w2 = 0; w2 < 6; ++w2) {
                tot += red[w2][t];
                Zt  += red[w2][16];
            }
            const float so = tot / Zt;         // s[o]
            float sq = so * so;                // 16-lane butterfly for ||s||^2
            #pragma unroll
            for (int off = 8; off >= 1; off >>= 1) sq += __shfl_xor(sq, off);
            const float fac = sqrtf(sq) / (1.f + sq);
            const float vo  = so * fac;
            if (it == 2) out[((size_t)bid << 4) + t] = vo;
            else         vfin[t] = vo;
        }
        if (it < 2) {
            __syncthreads();                   // barrier 2: vfin ready, red safe
            const float4 v0 = *reinterpret_cast<const float4*>(&vfin[0]);
            const float4 v1 = *reinterpret_cast<const float4*>(&vfin[4]);
            const float4 v2 = *reinterpret_cast<const float4*>(&vfin[8]);
            const float4 v3 = *reinterpret_cast<const float4*>(&vfin[12]);
            vprev[0]=v0.x;  vprev[1]=v0.y;  vprev[2]=v0.z;  vprev[3]=v0.w;
            vprev[4]=v1.x;  vprev[5]=v1.y;  vprev[6]=v1.z;  vprev[7]=v1.w;
            vprev[8]=v2.x;  vprev[9]=v2.y;  vprev[10]=v2.z; vprev[11]=v2.w;
            vprev[12]=v3.x; vprev[13]=v3.y; vprev[14]=v3.z; vprev[15]=v3.w;
        }
    }
}

extern "C" void kernel_launch(void* const* d_in, const int* in_sizes, int n_in,
                              void* d_out, int out_size, void* d_ws, size_t ws_size,
                              hipStream_t stream)
{
    const float* x   = (const float*)d_in[0];
    const float* W   = (const float*)d_in[1];
    float*       out = (float*)d_out;
    const size_t WH_BYTES = (size_t)10 * N_ROUTE * 128 * sizeof(__half);  // 2.95 MB

    if (ws_size >= WH_BYTES) {
        __half* Wh = (__half*)d_ws;
        convert_w<<<dim3(1440), dim3(256), 0, stream>>>(W, Wh);
        capsule_routing<true><<<dim3(10 * 256), dim3(NB), 0, stream>>>(x, W, Wh, out);
    } else {
        capsule_routing<false><<<dim3(10 * 256), dim3(NB), 0, stream>>>(x, W, nullptr, out);
    }
}

// Round 10
// 120.475 us; speedup vs baseline: 1.3224x; 1.1415x over previous
//
#include <hip/hip_runtime.h>
#include <hip/hip_fp16.h>

#define NB     384           // 6 waves; 1152 = 384*3 -> 3 rows/thread
#define ROWS   3
#define N_ROUTE 1152
#define RB     18            // row-blocks of 64 rows
#define NCHUNK 16            // uint4 chunks per row in Wh layout

typedef __fp16 half2v __attribute__((ext_vector_type(2)));

__device__ __forceinline__ float fdot2u(unsigned int a, unsigned int b, float c) {
#if __has_builtin(__builtin_amdgcn_fdot2)
    half2v ha, hb;
    __builtin_memcpy(&ha, &a, 4);
    __builtin_memcpy(&hb, &b, 4);
    return __builtin_amdgcn_fdot2(ha, hb, c, false);
#else
    const __half2 h_a = *reinterpret_cast<const __half2*>(&a);
    const __half2 h_b = *reinterpret_cast<const __half2*>(&b);
    return fmaf(__low2float(h_a), __low2float(h_b),
           fmaf(__high2float(h_a), __high2float(h_b), c));
#endif
}

__device__ __forceinline__ unsigned int pkh(float a, float b) {
    half2v h = __builtin_amdgcn_cvt_pkrtz(a, b);
    unsigned int u;
    __builtin_memcpy(&u, &h, 4);
    return u;
}

// 6-step DPP wave-64 sum; full sum lands in lane 63.
template<int CTRL>
__device__ __forceinline__ float dpp_add(float v) {
    int t = __builtin_amdgcn_update_dpp(0, __float_as_int(v), CTRL, 0xF, 0xF, true);
    return v + __int_as_float(t);
}
__device__ __forceinline__ float wave_sum63(float v) {
    v = dpp_add<0x111>(v);   // row_shr:1
    v = dpp_add<0x112>(v);   // row_shr:2
    v = dpp_add<0x114>(v);   // row_shr:4
    v = dpp_add<0x118>(v);   // row_shr:8
    v = dpp_add<0x142>(v);   // row_bcast:15
    v = dpp_add<0x143>(v);   // row_bcast:31
    return v;
}

// ---- Pre-pass: W fp32 -> fp16, per-thread-coalesced layout ----
// Wh chunk addr = ((c*18 + r)*16 + o)*64 + (n&63), r = n>>6.
// Chunk (uint4) = comp o of row n as 4 half2 i-pairs:
//   field ip = (W[c][n][2ip][o], W[c][n][2ip+1][o]).
// Main kernel: lane l reads chunk at +l -> 64 lanes = 1KB contiguous.
__global__ __launch_bounds__(256, 2)
void convert_w(const float* __restrict__ W, uint4* __restrict__ Wh)
{
    const int tid = blockIdx.x * 256 + threadIdx.x;   // 11520 = 10*1152
    const int c = tid / N_ROUTE;
    const int n = tid - c * N_ROUTE;
    const float* __restrict__ src = W + (size_t)tid * 128;
    unsigned int ch[16][4];
    #pragma unroll
    for (int ip = 0; ip < 4; ++ip) {
        float a[16], bb[16];
        #pragma unroll
        for (int q = 0; q < 4; ++q) {
            const float4 va = *reinterpret_cast<const float4*>(src + (2*ip)   * 16 + q*4);
            const float4 vb = *reinterpret_cast<const float4*>(src + (2*ip+1) * 16 + q*4);
            a[q*4+0]=va.x;  a[q*4+1]=va.y;  a[q*4+2]=va.z;  a[q*4+3]=va.w;
            bb[q*4+0]=vb.x; bb[q*4+1]=vb.y; bb[q*4+2]=vb.z; bb[q*4+3]=vb.w;
        }
        #pragma unroll
        for (int o = 0; o < 16; ++o) ch[o][ip] = pkh(a[o], bb[o]);
    }
    const int r = n >> 6, l = n & 63;
    uint4* __restrict__ dst = Wh + ((size_t)(c * RB + r) * NCHUNK) * 64 + l;
    #pragma unroll
    for (int o = 0; o < 16; ++o)
        dst[o * 64] = make_uint4(ch[o][0], ch[o][1], ch[o][2], ch[o][3]);
}

// ---- Main kernel: P fully register-resident (packed half2), no LDS P ----
__global__ __launch_bounds__(NB, 2)
void capsule_routing_reg(const float* __restrict__ x,
                         const uint4* __restrict__ Wh,
                         float* __restrict__ out)
{
    __shared__ float red[6][20];   // per-wave partials: 16 s + [16]=Z
    __shared__ float vfin[16];

    const int t    = threadIdx.x;
    const int bid  = blockIdx.x;
    const int c    = bid >> 8;
    const int b    = bid & 255;
    const int lane = t & 63;
    const int wid  = t >> 6;

    // ---- P-build: rows n = 64*(wid+6k)+lane, fully coalesced W reads ----
    unsigned int p2[ROWS][8];      // priors packed half2 (o-pairs)
    {
        const float* __restrict__ xb = x + (size_t)b * (N_ROUTE * 8);
        const uint4* __restrict__ Wc = Wh + (size_t)c * RB * NCHUNK * 64;
        #pragma unroll
        for (int k = 0; k < ROWS; ++k) {
            const int r = wid + 6 * k;
            const int n = (r << 6) + lane;
            const float4 x0 = *reinterpret_cast<const float4*>(xb + n * 8);
            const float4 x1 = *reinterpret_cast<const float4*>(xb + n * 8 + 4);
            const unsigned int xh[4] = { pkh(x0.x, x0.y), pkh(x0.z, x0.w),
                                         pkh(x1.x, x1.y), pkh(x1.z, x1.w) };
            const uint4* __restrict__ wr = Wc + (size_t)r * NCHUNK * 64 + lane;
            #pragma unroll
            for (int j = 0; j < 8; ++j) {          // o-pair (2j, 2j+1)
                const uint4 w0 = wr[(2 * j)     * 64];
                const uint4 w1 = wr[(2 * j + 1) * 64];
                float d0 = fdot2u(xh[0], w0.x, 0.f);
                d0 = fdot2u(xh[1], w0.y, d0);
                d0 = fdot2u(xh[2], w0.z, d0);
                d0 = fdot2u(xh[3], w0.w, d0);
                float d1 = fdot2u(xh[0], w1.x, 0.f);
                d1 = fdot2u(xh[1], w1.y, d1);
                d1 = fdot2u(xh[2], w1.z, d1);
                d1 = fdot2u(xh[3], w1.w, d1);
                p2[k][j] = pkh(d0, d1);
            }
        }
    }
    // No barrier: each thread owns its rows.

    float lg[ROWS] = {0.f, 0.f, 0.f};
    unsigned int vph[8] = {0, 0, 0, 0, 0, 0, 0, 0};  // packed v from prev iter

    #pragma unroll
    for (int it = 0; it < 3; ++it) {
        float sp[16];
        #pragma unroll
        for (int o = 0; o < 16; ++o) sp[o] = 0.f;
        float zp = (it == 0) ? (float)ROWS : 0.f;

        #pragma unroll
        for (int k = 0; k < ROWS; ++k) {
            float e;
            if (it == 0) {
                e = 1.f;                            // softmax of zeros = uniform
            } else {
                float d = 0.f;                      // logit += dot(P[n], v)
                #pragma unroll
                for (int j = 0; j < 8; ++j) d = fdot2u(p2[k][j], vph[j], d);
                lg[k] += d;
                e = __expf(lg[k]);                  // |lg| small; no max-sub
                zp += e;
            }
            #pragma unroll
            for (int j = 0; j < 8; ++j) {           // sp += e * P (fma_mix)
                const __half2 h = *reinterpret_cast<const __half2*>(&p2[k][j]);
                sp[2 * j]     = fmaf(e, __low2float(h),  sp[2 * j]);
                sp[2 * j + 1] = fmaf(e, __high2float(h), sp[2 * j + 1]);
            }
        }

        // 17-value wave reduction on the VALU pipe (DPP), result in lane 63
        #pragma unroll
        for (int o = 0; o < 16; ++o) sp[o] = wave_sum63(sp[o]);
        zp = wave_sum63(zp);
        if (lane == 63) {
            #pragma unroll
            for (int o = 0; o < 16; ++o) red[wid][o] = sp[o];
            red[wid][16] = zp;
        }
        __syncthreads();                            // barrier 1: red ready

        if (t < 16) {
            float tot = 0.f, Zt = 0.f;
            #pragma unroll
            for (int w2 = 0; w2 < 6; ++w2) {
                tot += red[w2][t];
                Zt  += red[w2][16];
            }
            const float so = tot / Zt;              // s[o]
            float sq = so * so;                     // 16-lane ||s||^2
            #pragma unroll
            for (int off = 8; off >= 1; off >>= 1) sq += __shfl_xor(sq, off);
            const float fac = sqrtf(sq) / (1.f + sq);
            const float vo  = so * fac;
            if (it == 2) out[((size_t)bid << 4) + t] = vo;
            else         vfin[t] = vo;
        }
        if (it < 2) {
            __syncthreads();                        // barrier 2: vfin ready
            const float4 v0 = *reinterpret_cast<const float4*>(&vfin[0]);
            const float4 v1 = *reinterpret_cast<const float4*>(&vfin[4]);
            const float4 v2 = *reinterpret_cast<const float4*>(&vfin[8]);
            const float4 v3 = *reinterpret_cast<const float4*>(&vfin[12]);
            vph[0] = pkh(v0.x, v0.y);  vph[1] = pkh(v0.z, v0.w);
            vph[2] = pkh(v1.x, v1.y);  vph[3] = pkh(v1.z, v1.w);
            vph[4] = pkh(v2.x, v2.y);  vph[5] = pkh(v2.z, v2.w);
            vph[6] = pkh(v3.x, v3.y);  vph[7] = pkh(v3.z, v3.w);
        }
    }
}

// ---- Fallback (ws too small): R8-style fp32-W + LDS-P kernel ----
__global__ __launch_bounds__(NB, 2)
void capsule_routing_lds(const float* __restrict__ x,
                         const float* __restrict__ W,
                         float* __restrict__ out)
{
    __shared__ unsigned int P[N_ROUTE * 8];
    __shared__ float red[6][20];
    __shared__ float vfin[16];

    const int t    = threadIdx.x;
    const int bid  = blockIdx.x;
    const int c    = bid >> 8;
    const int b    = bid & 255;
    const int lane = t & 63;
    const int wid  = t >> 6;

    {
        const int og = t & 3;
        const int nl = t >> 2;
        const float* __restrict__ xb = x + (size_t)b * (N_ROUTE * 8);
        const float* __restrict__ Wc = W + (size_t)c * (N_ROUTE * 128);
        #pragma unroll 2
        for (int pp = 0; pp < 12; ++pp) {
            const int n = pp * 96 + nl;
            const float4 x0 = *reinterpret_cast<const float4*>(xb + n * 8);
            const float4 x1 = *reinterpret_cast<const float4*>(xb + n * 8 + 4);
            const float xs[8] = {x0.x, x0.y, x0.z, x0.w, x1.x, x1.y, x1.z, x1.w};
            const float* __restrict__ wp = Wc + (size_t)n * 128 + (og << 2);
            float4 acc = make_float4(0.f, 0.f, 0.f, 0.f);
            #pragma unroll
            for (int i = 0; i < 8; ++i) {
                const float4 w = *reinterpret_cast<const float4*>(wp + i * 16);
                acc.x = fmaf(xs[i], w.x, acc.x);
                acc.y = fmaf(xs[i], w.y, acc.y);
                acc.z = fmaf(xs[i], w.z, acc.z);
                acc.w = fmaf(xs[i], w.w, acc.w);
            }
            const int s    = (n >> 2) & 7;
            const int base = n << 3;
            P[base + (((og << 1)    ) ^ s)] = pkh(acc.x, acc.y);
            P[base + (((og << 1) + 1) ^ s)] = pkh(acc.z, acc.w);
        }
    }
    __syncthreads();

    float vprev[16];
    #pragma unroll
    for (int o = 0; o < 16; ++o) vprev[o] = 0.f;
    float lg[ROWS] = {0.f, 0.f, 0.f};

    #pragma unroll
    for (int it = 0; it < 3; ++it) {
        float sp[16];
        #pragma unroll
        for (int o = 0; o < 16; ++o) sp[o] = 0.f;
        float zp = (it == 0) ? (float)ROWS : 0.f;

        #pragma unroll
        for (int k = 0; k < ROWS; ++k) {
            const int n = t + k * NB;
            const int s = (n >> 2) & 7;
            const unsigned int* __restrict__ pr = &P[n << 3];
            __half2 h[8];
            #pragma unroll
            for (int j = 0; j < 8; ++j) {
                const unsigned int w = pr[j ^ s];
                h[j] = *reinterpret_cast<const __half2*>(&w);
            }
            float e;
            if (it == 0) {
                e = 1.f;
            } else {
                float d = 0.f;
                #pragma unroll
                for (int j = 0; j < 8; ++j) {
                    d = fmaf(__low2float(h[j]),  vprev[2 * j],     d);
                    d = fmaf(__high2float(h[j]), vprev[2 * j + 1], d);
                }
                lg[k] += d;
                e = __expf(lg[k]);
                zp += e;
            }
            #pragma unroll
            for (int j = 0; j < 8; ++j) {
                sp[2 * j]     = fmaf(e, __low2float(h[j]),  sp[2 * j]);
                sp[2 * j + 1] = fmaf(e, __high2float(h[j]), sp[2 * j + 1]);
            }
        }

        #pragma unroll
        for (int o = 0; o < 16; ++o) sp[o] = wave_sum63(sp[o]);
        zp = wave_sum63(zp);
        if (lane == 63) {
            #pragma unroll
            for (int o = 0; o < 16; ++o) red[wid][o] = sp[o];
            red[wid][16] = zp;
        }
        __syncthreads();

        if (t < 16) {
            float tot = 0.f, Zt = 0.f;
            #pragma unroll
            for (int w2 = 0; w2 < 6; ++w2) { tot += red[w2][t]; Zt += red[w2][16]; }
            const float so = tot / Zt;
            float sq = so * so;
            #pragma unroll
            for (int off = 8; off >= 1; off >>= 1) sq += __shfl_xor(sq, off);
            const float fac = sqrtf(sq) / (1.f + sq);
            const float vo  = so * fac;
            if (it == 2) out[((size_t)bid << 4) + t] = vo;
            else         vfin[t] = vo;
        }
        if (it < 2) {
            __syncthreads();
            #pragma unroll
            for (int o = 0; o < 16; ++o) vprev[o] = vfin[o];
        }
    }
}

extern "C" void kernel_launch(void* const* d_in, const int* in_sizes, int n_in,
                              void* d_out, int out_size, void* d_ws, size_t ws_size,
                              hipStream_t stream)
{
    const float* x   = (const float*)d_in[0];
    const float* W   = (const float*)d_in[1];
    float*       out = (float*)d_out;
    const size_t WH_BYTES = (size_t)10 * RB * NCHUNK * 64 * sizeof(uint4);  // 2.95 MB

    if (ws_size >= WH_BYTES) {
        uint4* Wh = (uint4*)d_ws;
        convert_w<<<dim3(45), dim3(256), 0, stream>>>(W, Wh);
        capsule_routing_reg<<<dim3(10 * 256), dim3(NB), 0, stream>>>(x, Wh, out);
    } else {
        capsule_routing_lds<<<dim3(10 * 256), dim3(NB), 0, stream>>>(x, W, out);
    }
}